// Round 3
// baseline (376.851 us; speedup 1.0000x reference)
//
#include <hip/hip_runtime.h>

typedef __attribute__((ext_vector_type(8))) short bf16x8;
typedef __attribute__((ext_vector_type(4))) float f32x4;

#define LDS_TILE 32768          // A 256x32 bf16 (16KB) + B 256x32 bf16 (16KB)
#define NBUF 4
#define LDS_TOTAL (NBUF * LDS_TILE)   // 128 KB

__device__ __forceinline__ unsigned short f2bf(float f) {
  union { float f; unsigned u; } a; a.f = f;
  unsigned u = a.u;
  unsigned r = (u + 0x7FFFu + ((u >> 16) & 1u)) >> 16;  // round-nearest-even
  return (unsigned short)r;
}

__device__ __forceinline__ void stage16(const void* g, void* l) {
  __builtin_amdgcn_global_load_lds((const __attribute__((address_space(1))) unsigned int*)g,
                                   (__attribute__((address_space(3))) unsigned int*)l,
                                   16, 0, 0);
}

// ---------------------------------------------------------------------------
// NT GEMM, C[m,n] = scale * sum_k A[m,k]*B[n,k] (+bias)
// BM=BN=256, BK=32, 512 thr = 8 waves (2M x 4N), wave tile 128x64.
// 4-buffer K-step pipeline, depth-3 prefetch, vmcnt(8)+s_barrier per K-step.
// XOR-swizzled LDS (source-side pre-swizzle, linear global_load_lds dest):
//   stored_slot = logical_slot ^ f(row), f(r) = (r&3) ^ ((r>>2)&1)
// Requires: M%256==0, N%256==0, K%32==0, nt>=3, grid blocks %8==0.
// bias2: used when (tz&1) — enables fusing two N-outputs via gridDim.z.
// ---------------------------------------------------------------------------
template<bool OUT_BF16, int BIAS_MODE>
__global__ __launch_bounds__(512, 2) void gemm_nt(
    const unsigned short* __restrict__ A,
    const unsigned short* __restrict__ B,
    void* __restrict__ Cv,
    const float* __restrict__ bias,
    const float* __restrict__ bias2,
    float scale, int K,
    int lda, int ldb, int ldc,
    long batchA, long batchB, long batchC)
{
  extern __shared__ char smem[];

  // ---- bijective XCD-aware block swizzle (nwg % 8 == 0 for all our grids)
  const int gx = gridDim.x, gy = gridDim.y;
  int bid = blockIdx.x + gx * (blockIdx.y + gy * blockIdx.z);
  const int nwg = gx * gy * gridDim.z;
  const int q = nwg >> 3;
  int wg = (bid & 7) * q + (bid >> 3);
  const int tx = wg % gx;
  int rest = wg / gx;
  const int ty = rest % gy;
  const int tz = rest / gy;

  const int tid  = threadIdx.x;
  const int lane = tid & 63;
  const int wid  = tid >> 6;
  const int wm   = wid >> 2;     // 0..1 -> rows wm*128
  const int wn   = wid & 3;      // 0..3 -> cols wn*64

  A += (long)tz * batchA;
  B += (long)tz * batchB;
  const int tileM = tx * 256;
  const int tileN = ty * 256;

  // ---- staging source (pre-swizzled column slot). Thread covers row tid>>2
  // (128 rows per 512-thread load group), stored slot tid&3.
  const int srow = tid >> 2;                                   // 0..127
  const int fs   = ((srow & 3) ^ ((srow >> 2) & 1));           // f(row)
  const int scol = (((tid & 3) ^ fs) << 3);                    // elems
  const unsigned short* ga[2];
  const unsigned short* gb[2];
#pragma unroll
  for (int g = 0; g < 2; ++g) ga[g] = A + (size_t)(tileM + g * 128 + srow) * lda + scol;
#pragma unroll
  for (int g = 0; g < 2; ++g) gb[g] = B + (size_t)(tileN + g * 128 + srow) * ldb + scol;

  // ---- fragment read offsets (bytes within one buffer)
  const int fl   = lane & 15;
  const int fr   = ((fl & 3) ^ ((fl >> 2) & 1));               // f(row) for reads
  const int swz16 = (((lane >> 4) ^ fr) << 4);                 // stored slot * 16B
  const int paoff = (wm * 128 + fl) * 64 + swz16;
  const int pboff = 16384 + (wn * 64 + fl) * 64 + swz16;

  f32x4 acc[8][4];
#pragma unroll
  for (int m = 0; m < 8; ++m)
#pragma unroll
    for (int n = 0; n < 4; ++n) acc[m][n] = (f32x4){0.f, 0.f, 0.f, 0.f};

  const int nt = K >> 5;

#define STAGE(t)                                                            \
  do {                                                                      \
    char* d_ = smem + ((t) & 3) * LDS_TILE;                                 \
    const int kc_ = (t) << 5;                                               \
    _Pragma("unroll")                                                       \
    for (int g = 0; g < 2; ++g) stage16(ga[g] + kc_, d_ + g * 8192 + tid * 16); \
    _Pragma("unroll")                                                       \
    for (int g = 0; g < 2; ++g) stage16(gb[g] + kc_, d_ + 16384 + g * 8192 + tid * 16); \
  } while (0)

#define COMPUTE(t)                                                          \
  do {                                                                      \
    const char* d_ = smem + ((t) & 3) * LDS_TILE;                           \
    bf16x8 af[8], bfv[4];                                                   \
    _Pragma("unroll")                                                       \
    for (int m = 0; m < 8; ++m) af[m]  = *(const bf16x8*)(d_ + paoff + m * 1024); \
    _Pragma("unroll")                                                       \
    for (int n = 0; n < 4; ++n) bfv[n] = *(const bf16x8*)(d_ + pboff + n * 1024); \
    __builtin_amdgcn_s_setprio(1);                                          \
    _Pragma("unroll")                                                       \
    for (int m = 0; m < 8; ++m)                                             \
      _Pragma("unroll")                                                     \
      for (int n = 0; n < 4; ++n)                                           \
        acc[m][n] = __builtin_amdgcn_mfma_f32_16x16x32_bf16(af[m], bfv[n], acc[m][n], 0, 0, 0); \
    __builtin_amdgcn_s_setprio(0);                                          \
  } while (0)

  // prologue: 3 K-steps in flight (12 loads); wait oldest (tile 0) landed
  STAGE(0);
  STAGE(1);
  STAGE(2);
  asm volatile("s_waitcnt vmcnt(8)" ::: "memory");
  __builtin_amdgcn_s_barrier();

  for (int t = 0; t < nt - 3; ++t) {
    STAGE(t + 3);              // buf (t+3)&3: its last readers (tile t-1)
                               // finished before the barrier we just crossed
    COMPUTE(t);
    asm volatile("s_waitcnt vmcnt(8)" ::: "memory");   // tile t+1 landed
    __builtin_amdgcn_s_barrier();
  }
  COMPUTE(nt - 3);
  asm volatile("s_waitcnt vmcnt(4)" ::: "memory");     // tile nt-2 landed
  __builtin_amdgcn_s_barrier();
  COMPUTE(nt - 2);
  asm volatile("s_waitcnt vmcnt(0)" ::: "memory");     // tile nt-1 landed
  __builtin_amdgcn_s_barrier();
  COMPUTE(nt - 1);

#undef STAGE
#undef COMPUTE

  // ---- epilogue. C/D: col = lane&15, row = (lane>>4)*4 + reg  [m89]
  const float* bptr = (tz & 1) ? bias2 : bias;
  const int ro = (lane >> 4) << 2;
  const int co = lane & 15;
#pragma unroll
  for (int m = 0; m < 8; ++m) {
#pragma unroll
    for (int n = 0; n < 4; ++n) {
      const int row0 = tileM + wm * 128 + m * 16 + ro;
      const int col  = tileN + wn * 64 + n * 16 + co;
#pragma unroll
      for (int r = 0; r < 4; ++r) {
        float v = acc[m][n][r] * scale;
        const int row = row0 + r;
        if (BIAS_MODE == 1) v += bptr[col];
        if (BIAS_MODE == 2) v += bptr[row];
        const size_t ci = (size_t)(tz * batchC) + (size_t)row * ldc + col;
        if (OUT_BF16) ((unsigned short*)Cv)[ci] = f2bf(v);
        else          ((float*)Cv)[ci] = v;
      }
    }
  }
}

// ---------------------------------------------------------------------------
// Row softmax over 2048 fp32 scores + intensity add, bf16 written IN-PLACE
// (attn row i at bf16-elem offset i*4096). One 256-thr block per row.
// ---------------------------------------------------------------------------
__global__ __launch_bounds__(256) void softmax_add_bf16(
    float* __restrict__ scores, const float* __restrict__ inten)
{
  const int row = blockIdx.x;
  float* srow = scores + (size_t)row * 2048;
  const float* irow = inten + (size_t)row * 2048;
  const int t = threadIdx.x;
  const int lane = t & 63, wid = t >> 6;

  float v[8];
  float mx = -3.4e38f;
#pragma unroll
  for (int j = 0; j < 8; ++j) { v[j] = srow[t + j * 256]; mx = fmaxf(mx, v[j]); }

  __shared__ float red[8];
#pragma unroll
  for (int o = 32; o; o >>= 1) mx = fmaxf(mx, __shfl_xor(mx, o));
  if (lane == 0) red[wid] = mx;
  __syncthreads();
  mx = fmaxf(fmaxf(red[0], red[1]), fmaxf(red[2], red[3]));

  float s = 0.f;
#pragma unroll
  for (int j = 0; j < 8; ++j) { v[j] = __expf(v[j] - mx); s += v[j]; }
#pragma unroll
  for (int o = 32; o; o >>= 1) s += __shfl_xor(s, o);
  if (lane == 0) red[4 + wid] = s;
  __syncthreads();
  s = red[4] + red[5] + red[6] + red[7];
  const float inv = 1.f / s;

  unsigned short* arow = (unsigned short*)srow;   // in-place bf16, stride 4096
#pragma unroll
  for (int j = 0; j < 8; ++j)
    arow[t + j * 256] = f2bf(v[j] * inv + irow[t + j * 256]);
}

__global__ __launch_bounds__(256) void cvt_bf16(
    const float* __restrict__ in, unsigned short* __restrict__ out, int n)
{
  const int i = (blockIdx.x * 256 + threadIdx.x) * 4;
  if (i >= n) return;
  const float4 f = *(const float4*)(in + i);
  ushort4 o;
  o.x = f2bf(f.x); o.y = f2bf(f.y); o.z = f2bf(f.z); o.w = f2bf(f.w);
  *(ushort4*)(out + i) = o;
}

extern "C" void kernel_launch(void* const* d_in, const int* in_sizes, int n_in,
                              void* d_out, int out_size, void* d_ws, size_t ws_size,
                              hipStream_t stream)
{
  const float* X     = (const float*)d_in[0];
  const float* inten = (const float*)d_in[1];
  const float* Wq = (const float*)d_in[2];
  const float* bq = (const float*)d_in[3];
  const float* Wk = (const float*)d_in[4];
  const float* bk = (const float*)d_in[5];
  const float* Wv = (const float*)d_in[6];
  const float* bv = (const float*)d_in[7];
  const float* Wo = (const float*)d_in[8];
  const float* bo = (const float*)d_in[9];
  float* out = (float*)d_out;

  const int B = 4, S = 2048, D = 1024;
  const int MS = B * S;                 // 8192
  char* ws = (char*)d_ws;
  const size_t MB = 1 << 20;
  unsigned short* Xb  = (unsigned short*)(ws);              // 16 MB
  unsigned short* Wqb = (unsigned short*)(ws + 16 * MB);    //  2 MB
  unsigned short* Wkb = (unsigned short*)(ws + 18 * MB);    //  2 MB (contiguous after Wqb)
  unsigned short* Wvb = (unsigned short*)(ws + 20 * MB);
  unsigned short* Wob = (unsigned short*)(ws + 22 * MB);
  unsigned short* Q   = (unsigned short*)(ws + 24 * MB);    // 16 MB
  unsigned short* Kb  = (unsigned short*)(ws + 40 * MB);    // 16 MB
  unsigned short* Vt  = (unsigned short*)(ws + 56 * MB);    // 16 MB  [B][D][S]
  unsigned short* Oa  = (unsigned short*)(ws + 72 * MB);    // 16 MB
  float*          Sc  = (float*)(ws + 88 * MB);             // 64 MB  [B][S][S]

  // allow 128 KB dynamic LDS (idempotent, capture-safe)
  hipFuncSetAttribute((const void*)gemm_nt<true, 1>,  hipFuncAttributeMaxDynamicSharedMemorySize, LDS_TOTAL);
  hipFuncSetAttribute((const void*)gemm_nt<true, 2>,  hipFuncAttributeMaxDynamicSharedMemorySize, LDS_TOTAL);
  hipFuncSetAttribute((const void*)gemm_nt<false, 0>, hipFuncAttributeMaxDynamicSharedMemorySize, LDS_TOTAL);
  hipFuncSetAttribute((const void*)gemm_nt<true, 0>,  hipFuncAttributeMaxDynamicSharedMemorySize, LDS_TOTAL);
  hipFuncSetAttribute((const void*)gemm_nt<false, 1>, hipFuncAttributeMaxDynamicSharedMemorySize, LDS_TOTAL);

  // 1) fp32 -> bf16 conversions
  cvt_bf16<<<(MS * D) / 1024, 256, 0, stream>>>(X,  Xb,  MS * D);
  cvt_bf16<<<(D * D) / 1024, 256, 0, stream>>>(Wq, Wqb, D * D);
  cvt_bf16<<<(D * D) / 1024, 256, 0, stream>>>(Wk, Wkb, D * D);
  cvt_bf16<<<(D * D) / 1024, 256, 0, stream>>>(Wv, Wvb, D * D);
  cvt_bf16<<<(D * D) / 1024, 256, 0, stream>>>(Wo, Wob, D * D);

  // 2) fused Q&K: z=0 -> Q = Xb@Wq^T + bq ; z=1 -> K = Xb@Wk^T + bk
  //    (Wkb contiguous after Wqb: batchB = 1M elems; Kb after Q: batchC = 8M)
  dim3 gqk(MS / 256, D / 256, 2);     // 32x4x2 = 256 blocks
  gemm_nt<true, 1><<<gqk, 512, LDS_TOTAL, stream>>>(
      Xb, Wqb, Q, bq, bk, 1.f, D, D, D, D,
      0, (long)(Wkb - Wqb), (long)(Kb - Q));

  // 3) Vt[b] = Wv @ X[b]^T + bv (row bias)         [B][1024][2048] bf16
  dim3 gvt(D / 256, S / 256, B);      // 4x8x4 = 128 blocks
  gemm_nt<true, 2><<<gvt, 512, LDS_TOTAL, stream>>>(
      Wvb, Xb, Vt, bv, bv, 1.f, D, D, D, S,
      0, (long)S * D, (long)D * S);

  // 4) scores[b] = Q[b] @ K[b]^T / 32              [B][2048][2048] fp32
  dim3 gsc(S / 256, S / 256, B);      // 8x8x4 = 256 blocks
  gemm_nt<false, 0><<<gsc, 512, LDS_TOTAL, stream>>>(
      Q, Kb, Sc, nullptr, nullptr, 0.03125f, D, D, D, S,
      (long)S * D, (long)S * D, (long)S * S);

  // 5) attn = softmax(scores) + intensity, bf16 in-place (row stride 4096)
  softmax_add_bf16<<<B * S, 256, 0, stream>>>(Sc, inten);

  // 6) Oa[b] = attn[b] @ Vt[b]^T                   [B][2048][1024] bf16
  dim3 gav(S / 256, D / 256, B);      // 8x4x4 = 128 blocks
  gemm_nt<true, 0><<<gav, 512, LDS_TOTAL, stream>>>(
      (unsigned short*)Sc, Vt, Oa, nullptr, nullptr, 1.f, S, 2 * S, S, D,
      (long)S * 2 * S, (long)D * S, (long)S * D);

  // 7) out = Oa @ Wo^T + bo                        [8192,1024] fp32
  dim3 gout(MS / 256, D / 256, 1);    // 32x4 = 128 blocks
  gemm_nt<false, 1><<<gout, 512, LDS_TOTAL, stream>>>(
      Oa, Wob, out, bo, bo, 1.f, D, D, D, D, 0, 0, 0);
}

// Round 6
// 344.162 us; speedup vs baseline: 1.0950x; 1.0950x over previous
//
#include <hip/hip_runtime.h>

typedef __attribute__((ext_vector_type(8))) short bf16x8;
typedef __attribute__((ext_vector_type(4))) float f32x4;

#define LDS_TILE (48 * 1024)   // A 256x64 bf16 (32KB) + B 128x64 bf16 (16KB)
#define NBUF 3
#define LDS_TOTAL (NBUF * LDS_TILE)   // 144 KB

__device__ __forceinline__ unsigned short f2bf(float f) {
  union { float f; unsigned u; } a; a.f = f;
  unsigned u = a.u;
  unsigned r = (u + 0x7FFFu + ((u >> 16) & 1u)) >> 16;  // round-nearest-even
  return (unsigned short)r;
}

__device__ __forceinline__ float bf2f(unsigned short s) {
  union { unsigned u; float f; } c; c.u = ((unsigned)s) << 16;
  return c.f;
}

__device__ __forceinline__ void stage16(const void* g, void* l) {
  __builtin_amdgcn_global_load_lds((const __attribute__((address_space(1))) unsigned int*)g,
                                   (__attribute__((address_space(3))) unsigned int*)l,
                                   16, 0, 0);
}

// ---------------------------------------------------------------------------
// NT GEMM, C[m,n] = scale * sum_k A[m,k]*B[n,k] (+bias)   [R2-proven structure]
// BM=256, BN=128, BK=64, 512 thr = 8 waves (4M x 2N, each 64x64 out).
// 3-buffer LDS pipeline, depth-2 prefetch, vmcnt(6)+s_barrier per K-tile.
// XOR-swizzled LDS (source-side pre-swizzle, linear global_load_lds dest).
// Requires: M%256==0, N%128==0, K%64==0, nt>=2, grid blocks %8==0.
// bias2 used when (tz&1) — for fusing two outputs via gridDim.z.
// ---------------------------------------------------------------------------
template<bool OUT_BF16, int BIAS_MODE>
__global__ __launch_bounds__(512) void gemm_nt(
    const unsigned short* __restrict__ A,
    const unsigned short* __restrict__ B,
    void* __restrict__ Cv,
    const float* __restrict__ bias,
    const float* __restrict__ bias2,
    float scale, int K,
    int lda, int ldb, int ldc,
    long batchA, long batchB, long batchC)
{
  extern __shared__ char smem[];

  // ---- bijective XCD-aware block swizzle (nwg % 8 == 0 for all our grids)
  const int gx = gridDim.x, gy = gridDim.y;
  int bid = blockIdx.x + gx * (blockIdx.y + gy * blockIdx.z);
  const int nwg = gx * gy * gridDim.z;
  const int q = nwg >> 3;
  int wg = (bid & 7) * q + (bid >> 3);
  const int tx = wg % gx;
  int rest = wg / gx;
  const int ty = rest % gy;
  const int tz = rest / gy;

  const int tid  = threadIdx.x;
  const int lane = tid & 63;
  const int wid  = tid >> 6;
  const int wm   = wid & 3;      // 0..3 -> rows wm*64
  const int wn   = wid >> 2;     // 0..1 -> cols wn*64

  A += (long)tz * batchA;
  B += (long)tz * batchB;
  const int tileM = tx * 256;
  const int tileN = ty * 128;

  // ---- staging source (pre-swizzled column slot)
  const int srow = tid >> 3;                          // 0..63
  const int scol = (((tid & 7) ^ (srow & 7)) << 3);   // swizzled col (elems)
  const unsigned short* ga[4];
  const unsigned short* gb[2];
#pragma unroll
  for (int j = 0; j < 4; ++j) ga[j] = A + (size_t)(tileM + j * 64 + srow) * lda + scol;
#pragma unroll
  for (int j = 0; j < 2; ++j) gb[j] = B + (size_t)(tileN + j * 64 + srow) * ldb + scol;

  // ---- fragment read offsets (bytes inside a buffer), XOR-swizzled
  const int frow  = lane & 15;
  const int k0slot = (lane >> 4) ^ (lane & 7);        // ksub=1 -> ^4
  const int aoff = (wm * 64 + frow) * 128;            // + m*2048 + slot*16
  const int boff = 32768 + (wn * 64 + frow) * 128;    // + n*2048 + slot*16

  f32x4 acc[4][4];
#pragma unroll
  for (int m = 0; m < 4; ++m)
#pragma unroll
    for (int n = 0; n < 4; ++n) acc[m][n] = (f32x4){0.f, 0.f, 0.f, 0.f};

  const int nt = K >> 6;

#define STAGE(t)                                                         \
  do {                                                                   \
    char* d_ = smem + ((t) % NBUF) * LDS_TILE;                           \
    const int kc_ = (t) << 6;                                            \
    _Pragma("unroll")                                                    \
    for (int j = 0; j < 4; ++j) stage16(ga[j] + kc_, d_ + j * 8192 + tid * 16); \
    _Pragma("unroll")                                                    \
    for (int j = 0; j < 2; ++j) stage16(gb[j] + kc_, d_ + 32768 + j * 8192 + tid * 16); \
  } while (0)

#define COMPUTE(t)                                                       \
  do {                                                                   \
    const char* d_ = smem + ((t) % NBUF) * LDS_TILE;                     \
    bf16x8 af[4][2], bfr[4][2];                                          \
    _Pragma("unroll")                                                    \
    for (int ks = 0; ks < 2; ++ks) {                                     \
      const int so_ = ((k0slot ^ (ks << 2)) << 4);                       \
      _Pragma("unroll")                                                  \
      for (int m = 0; m < 4; ++m)                                        \
        af[m][ks] = *(const bf16x8*)(d_ + aoff + m * 2048 + so_);        \
      _Pragma("unroll")                                                  \
      for (int n = 0; n < 4; ++n)                                        \
        bfr[n][ks] = *(const bf16x8*)(d_ + boff + n * 2048 + so_);       \
    }                                                                    \
    __builtin_amdgcn_s_setprio(1);                                       \
    _Pragma("unroll")                                                    \
    for (int ks = 0; ks < 2; ++ks)                                       \
      _Pragma("unroll")                                                  \
      for (int m = 0; m < 4; ++m)                                        \
        _Pragma("unroll")                                                \
        for (int n = 0; n < 4; ++n)                                      \
          acc[m][n] = __builtin_amdgcn_mfma_f32_16x16x32_bf16(af[m][ks], bfr[n][ks], acc[m][n], 0, 0, 0); \
    __builtin_amdgcn_s_setprio(0);                                       \
  } while (0)

  // prologue: stage tiles 0,1; wait tile0 (6 newest = tile1 may fly)
  STAGE(0);
  STAGE(1);
  asm volatile("s_waitcnt vmcnt(6)" ::: "memory");
  __builtin_amdgcn_s_barrier();

  for (int t = 0; t < nt - 2; ++t) {
    STAGE(t + 2);                 // into buf (t+2)%3 — not read by anyone now
    COMPUTE(t);
    asm volatile("s_waitcnt vmcnt(6)" ::: "memory");   // tile t+1 landed
    __builtin_amdgcn_s_barrier();
  }
  COMPUTE(nt - 2);
  asm volatile("s_waitcnt vmcnt(0)" ::: "memory");     // tile nt-1 landed
  __builtin_amdgcn_s_barrier();
  COMPUTE(nt - 1);

#undef STAGE
#undef COMPUTE

  // ---- epilogue. C/D: col = lane&15, row = (lane>>4)*4 + reg  [m89]
  const float* bptr = (tz & 1) ? bias2 : bias;
  const int ro = (lane >> 4) << 2;
  const int co = lane & 15;
#pragma unroll
  for (int m = 0; m < 4; ++m) {
#pragma unroll
    for (int n = 0; n < 4; ++n) {
      const int row0 = tileM + wm * 64 + m * 16 + ro;
      const int col  = tileN + wn * 64 + n * 16 + co;
#pragma unroll
      for (int r = 0; r < 4; ++r) {
        float v = acc[m][n][r] * scale;
        const int row = row0 + r;
        if (BIAS_MODE == 1) v += bptr[col];
        if (BIAS_MODE == 2) v += bptr[row];
        const size_t ci = (size_t)(tz * batchC) + (size_t)row * ldc + col;
        if (OUT_BF16) ((unsigned short*)Cv)[ci] = f2bf(v);
        else          ((float*)Cv)[ci] = v;
      }
    }
  }
}

// ---------------------------------------------------------------------------
// Row softmax over 2048 bf16 scores + fp32 intensity add, bf16 out (contig).
// One 256-thr block per row; thread handles 8 contiguous elems (16B loads).
// ---------------------------------------------------------------------------
__global__ __launch_bounds__(256) void softmax_add_bf16(
    const unsigned short* __restrict__ scores,
    const float* __restrict__ inten,
    unsigned short* __restrict__ attn)
{
  const int row = blockIdx.x;
  const unsigned short* srow = scores + (size_t)row * 2048;
  const float* irow = inten + (size_t)row * 2048;
  unsigned short* arow = attn + (size_t)row * 2048;
  const int t = threadIdx.x;
  const int lane = t & 63, wid = t >> 6;

  const bf16x8 raw = *(const bf16x8*)(srow + t * 8);
  float v[8];
  float mx = -3.4e38f;
#pragma unroll
  for (int j = 0; j < 8; ++j) {
    v[j] = bf2f((unsigned short)raw[j]);
    mx = fmaxf(mx, v[j]);
  }

  __shared__ float red[8];
#pragma unroll
  for (int o = 32; o; o >>= 1) mx = fmaxf(mx, __shfl_xor(mx, o));
  if (lane == 0) red[wid] = mx;
  __syncthreads();
  mx = fmaxf(fmaxf(red[0], red[1]), fmaxf(red[2], red[3]));

  float s = 0.f;
#pragma unroll
  for (int j = 0; j < 8; ++j) { v[j] = __expf(v[j] - mx); s += v[j]; }
#pragma unroll
  for (int o = 32; o; o >>= 1) s += __shfl_xor(s, o);
  if (lane == 0) red[4 + wid] = s;
  __syncthreads();
  s = red[4] + red[5] + red[6] + red[7];
  const float inv = 1.f / s;

  const float4 i0 = *(const float4*)(irow + t * 8);
  const float4 i1 = *(const float4*)(irow + t * 8 + 4);
  const float ia[8] = {i0.x, i0.y, i0.z, i0.w, i1.x, i1.y, i1.z, i1.w};
  bf16x8 o;
#pragma unroll
  for (int j = 0; j < 8; ++j) o[j] = (short)f2bf(v[j] * inv + ia[j]);
  *(bf16x8*)(arow + t * 8) = o;
}

__global__ __launch_bounds__(256) void cvt_bf16(
    const float* __restrict__ in, unsigned short* __restrict__ out, int n)
{
  const int i = (blockIdx.x * 256 + threadIdx.x) * 4;
  if (i >= n) return;
  const float4 f = *(const float4*)(in + i);
  ushort4 o;
  o.x = f2bf(f.x); o.y = f2bf(f.y); o.z = f2bf(f.z); o.w = f2bf(f.w);
  *(ushort4*)(out + i) = o;
}

// 4 weight matrices (1M fp32 elems each) -> contiguous bf16 (4M elems)
__global__ __launch_bounds__(256) void cvt_w4(
    const float* __restrict__ w0, const float* __restrict__ w1,
    const float* __restrict__ w2, const float* __restrict__ w3,
    unsigned short* __restrict__ out)
{
  const int b = blockIdx.x;          // 4096 blocks, 1024 per weight
  const int w = b >> 10;
  const float* src = (w == 0) ? w0 : (w == 1) ? w1 : (w == 2) ? w2 : w3;
  const int local = ((b & 1023) * 256 + threadIdx.x) * 4;
  const float4 f = *(const float4*)(src + local);
  ushort4 o;
  o.x = f2bf(f.x); o.y = f2bf(f.y); o.z = f2bf(f.z); o.w = f2bf(f.w);
  *(ushort4*)(out + (size_t)w * 1048576 + local) = o;
}

extern "C" void kernel_launch(void* const* d_in, const int* in_sizes, int n_in,
                              void* d_out, int out_size, void* d_ws, size_t ws_size,
                              hipStream_t stream)
{
  const float* X     = (const float*)d_in[0];
  const float* inten = (const float*)d_in[1];
  const float* Wq = (const float*)d_in[2];
  const float* bq = (const float*)d_in[3];
  const float* Wk = (const float*)d_in[4];
  const float* bk = (const float*)d_in[5];
  const float* Wv = (const float*)d_in[6];
  const float* bv = (const float*)d_in[7];
  const float* Wo = (const float*)d_in[8];
  const float* bo = (const float*)d_in[9];
  float* out = (float*)d_out;

  const int B = 4, S = 2048, D = 1024;
  const int MS = B * S;                 // 8192
  char* ws = (char*)d_ws;
  const size_t MB = 1 << 20;
  unsigned short* Xb  = (unsigned short*)(ws);              // 16 MB
  unsigned short* Wqb = (unsigned short*)(ws + 16 * MB);    // 2 MB (W's contiguous)
  unsigned short* Wkb = (unsigned short*)(ws + 18 * MB);
  unsigned short* Wvb = (unsigned short*)(ws + 20 * MB);
  unsigned short* Wob = (unsigned short*)(ws + 22 * MB);
  unsigned short* Q   = (unsigned short*)(ws + 24 * MB);    // 16 MB
  unsigned short* Kb  = (unsigned short*)(ws + 40 * MB);    // 16 MB
  unsigned short* Vt  = (unsigned short*)(ws + 56 * MB);    // 16 MB  [B][D][S]
  unsigned short* Oa  = (unsigned short*)(ws + 72 * MB);    // 16 MB
  unsigned short* Sc  = (unsigned short*)(ws + 88 * MB);    // 32 MB  bf16 [B][S][S]
  unsigned short* At  = (unsigned short*)(ws + 120 * MB);   // 32 MB  bf16 [B][S][S]

  // allow 144 KB dynamic LDS (idempotent, capture-safe)
  hipFuncSetAttribute((const void*)gemm_nt<true, 1>,  hipFuncAttributeMaxDynamicSharedMemorySize, LDS_TOTAL);
  hipFuncSetAttribute((const void*)gemm_nt<true, 2>,  hipFuncAttributeMaxDynamicSharedMemorySize, LDS_TOTAL);
  hipFuncSetAttribute((const void*)gemm_nt<true, 0>,  hipFuncAttributeMaxDynamicSharedMemorySize, LDS_TOTAL);
  hipFuncSetAttribute((const void*)gemm_nt<false, 1>, hipFuncAttributeMaxDynamicSharedMemorySize, LDS_TOTAL);

  // 1) fp32 -> bf16 conversions (X + all four weights in one dispatch)
  cvt_bf16<<<(MS * D) / 1024, 256, 0, stream>>>(X, Xb, MS * D);
  cvt_w4<<<4096, 256, 0, stream>>>(Wq, Wk, Wv, Wo, Wqb);

  // 2) fused Q&K: z=0 -> Q = Xb@Wq^T + bq ; z=1 -> K = Xb@Wk^T + bk
  dim3 gqk(MS / 256, D / 128, 2);     // 32x8x2 = 512 blocks
  gemm_nt<true, 1><<<gqk, 512, LDS_TOTAL, stream>>>(
      Xb, Wqb, Q, bq, bk, 1.f, D, D, D, D,
      0, (long)(Wkb - Wqb), (long)(Kb - Q));

  // 3) Vt[b] = Wv @ X[b]^T + bv (row bias)         [B][1024][2048] bf16
  dim3 gvt(D / 256, S / 128, B);      // 4x16x4 = 256 blocks
  gemm_nt<true, 2><<<gvt, 512, LDS_TOTAL, stream>>>(
      Wvb, Xb, Vt, bv, bv, 1.f, D, D, D, S,
      0, (long)S * D, (long)D * S);

  // 4) scores[b] = Q[b] @ K[b]^T / 32              [B][2048][2048] bf16
  dim3 gsc(S / 256, S / 128, B);      // 8x16x4 = 512 blocks
  gemm_nt<true, 0><<<gsc, 512, LDS_TOTAL, stream>>>(
      Q, Kb, Sc, nullptr, nullptr, 0.03125f, D, D, D, S,
      (long)S * D, (long)S * D, (long)S * S);

  // 5) attn = softmax(scores) + intensity -> At (contiguous bf16)
  softmax_add_bf16<<<B * S, 256, 0, stream>>>(Sc, inten, At);

  // 6) Oa[b] = attn[b] @ Vt[b]^T                   [B][2048][1024] bf16
  dim3 gav(S / 256, D / 128, B);      // 8x8x4 = 256 blocks
  gemm_nt<true, 0><<<gav, 512, LDS_TOTAL, stream>>>(
      At, Vt, Oa, nullptr, nullptr, 1.f, S, S, S, D,
      (long)S * S, (long)D * S, (long)S * D);

  // 7) out = Oa @ Wo^T + bo                        [8192,1024] fp32
  dim3 gout(MS / 256, D / 128, 1);    // 32x8 = 256 blocks
  gemm_nt<false, 1><<<gout, 512, LDS_TOTAL, stream>>>(
      Oa, Wob, out, bo, bo, 1.f, D, D, D, D, 0, 0, 0);
}